// Round 1
// baseline (486.525 us; speedup 1.0000x reference)
//
#include <hip/hip_runtime.h>
#include <math.h>

#define PI_F 3.14159265358979323846f

// ---------------------------------------------------------------------------
// QCNN: one block (128 threads) per sample, 8-qubit state (256 c64) in LDS.
// Qubit q maps to bit position (7-q) of the flat index (C-order of (2,)*8).
// ---------------------------------------------------------------------------

// general single-qubit gate; 128 threads each own one amplitude pair (in-place
// safe: pairs are disjoint). Caller relies on the trailing barrier.
__device__ __forceinline__ void ap1g(float2* st, int q,
                                     float2 u00, float2 u01,
                                     float2 u10, float2 u11) {
    int tid = threadIdx.x;            // 0..127
    int p = 7 - q;
    int m = 1 << p;
    int i0 = ((tid >> p) << (p + 1)) | (tid & (m - 1));
    int i1 = i0 | m;
    float2 a = st[i0], b = st[i1];
    float2 r0 = make_float2(u00.x * a.x - u00.y * a.y + u01.x * b.x - u01.y * b.y,
                            u00.x * a.y + u00.y * a.x + u01.x * b.y + u01.y * b.x);
    float2 r1 = make_float2(u10.x * a.x - u10.y * a.y + u11.x * b.x - u11.y * b.y,
                            u10.x * a.y + u10.y * a.x + u11.x * b.y + u11.y * b.x);
    st[i0] = r0;
    st[i1] = r1;
    __syncthreads();
}

__device__ __forceinline__ void aprz(float2* st, int q, float t) {
    float c = cosf(0.5f * t), s = sinf(0.5f * t);
    ap1g(st, q, make_float2(c, -s), make_float2(0.f, 0.f),
                make_float2(0.f, 0.f), make_float2(c, s));
}

__device__ __forceinline__ void apry(float2* st, int q, float t) {
    float c = cosf(0.5f * t), s = sinf(0.5f * t);
    ap1g(st, q, make_float2(c, 0.f), make_float2(-s, 0.f),
                make_float2(s, 0.f), make_float2(c, 0.f));
}

// CNOT control qc, target qt: swap amplitudes with (control=1, target=0/1).
__device__ __forceinline__ void apcx(float2* st, int qc, int qt) {
    int tid = threadIdx.x;
    if (tid < 64) {
        int pc = 7 - qc, pt = 7 - qt;
        int lo = pc < pt ? pc : pt;
        int hi = pc < pt ? pt : pc;
        int v = tid;  // 6 free bits
        v = ((v >> lo) << (lo + 1)) | (v & ((1 << lo) - 1));
        v = ((v >> hi) << (hi + 1)) | (v & ((1 << hi) - 1));
        int i = v | (1 << pc);        // control=1, target=0
        int j = i | (1 << pt);        // control=1, target=1
        float2 tmp = st[i];
        st[i] = st[j];
        st[j] = tmp;
    }
    __syncthreads();
}

__device__ void conv_blk(float2* st, const float* __restrict__ p, int q1, int q2) {
    aprz(st, q2, -0.5f * PI_F);
    apcx(st, q2, q1);
    aprz(st, q1, p[0]);
    apry(st, q2, p[1]);
    apcx(st, q1, q2);
    apry(st, q2, p[2]);
    apcx(st, q2, q1);
    aprz(st, q1, 0.5f * PI_F);
}

__device__ void pool_blk(float2* st, const float* __restrict__ p, int src, int sink) {
    aprz(st, sink, -0.5f * PI_F);
    apcx(st, sink, src);
    aprz(st, src, p[0]);
    apry(st, sink, p[1]);
    apcx(st, src, sink);
    apry(st, sink, p[2]);
}

__global__ __launch_bounds__(128) void qcnn_kernel(const float* __restrict__ x,
                                                   const float* __restrict__ w,
                                                   float* __restrict__ out) {
    __shared__ float2 st[256];
    __shared__ float wsum[2];
    int n = blockIdx.x;
    int tid = threadIdx.x;

    st[tid] = make_float2(0.f, 0.f);
    st[tid + 128] = make_float2(0.f, 0.f);
    if (tid == 0) st[0] = make_float2(1.f, 0.f);
    __syncthreads();

    // Fused ZFeatureMap reps=2: per qubit U = P(2x)·H·P(2x)·H
    const float* xr = x + n * 8;
    for (int q = 0; q < 8; ++q) {
        float phi = 2.0f * xr[q];
        float e1x = cosf(phi), e1y = sinf(phi);
        float e2x = e1x * e1x - e1y * e1y;   // e^{2i phi}
        float e2y = 2.0f * e1x * e1y;
        float2 u00 = make_float2(0.5f * (1.0f + e1x), 0.5f * e1y);
        float2 u01 = make_float2(0.5f * (1.0f - e1x), -0.5f * e1y);
        float2 u10 = make_float2(0.5f * (e1x - e2x), 0.5f * (e1y - e2y));
        float2 u11 = make_float2(0.5f * (e1x + e2x), 0.5f * (e1y + e2y));
        ap1g(st, q, u00, u01, u10, u11);
    }

    // c1
    conv_blk(st, w + 0, 0, 1);
    conv_blk(st, w + 3, 2, 3);
    conv_blk(st, w + 6, 4, 5);
    conv_blk(st, w + 9, 6, 7);
    // p1
    pool_blk(st, w + 12, 0, 1);
    pool_blk(st, w + 15, 2, 3);
    pool_blk(st, w + 18, 4, 5);
    pool_blk(st, w + 21, 6, 7);
    // c2
    conv_blk(st, w + 24, 0, 1);
    conv_blk(st, w + 27, 2, 3);
    // p2
    pool_blk(st, w + 30, 0, 1);
    pool_blk(st, w + 33, 2, 3);
    // c3
    conv_blk(st, w + 36, 0, 1);
    // p3
    pool_blk(st, w + 39, 0, 1);

    // <Z_7>: qubit 7 = LSB of flat index
    float2 a = st[2 * tid];
    float2 b = st[2 * tid + 1];
    float part = (a.x * a.x + a.y * a.y) - (b.x * b.x + b.y * b.y);
    #pragma unroll
    for (int off = 32; off > 0; off >>= 1)
        part += __shfl_down(part, off, 64);
    if ((tid & 63) == 0) wsum[tid >> 6] = part;
    __syncthreads();
    if (tid == 0) out[n] = wsum[0] + wsum[1];
}

// ---------------------------------------------------------------------------
// QLSTM: closed-form qgate. With a_i = v_i + theta_i, c_i = cos(a_i):
//   out = [c1*c2*c3, c0*c1, c0*c1*c2, c0*c1*c2*c3]
// (product state -> CNOT chain is a GF(2) basis permutation -> parity products)
// One lane per batch element (B=16); 128 sequential steps in registers.
// ---------------------------------------------------------------------------

__device__ __forceinline__ float sigf(float v) { return 1.0f / (1.0f + expf(-v)); }

__device__ __forceinline__ void qgate4(const float cb[5], const float* W,
                                       const float* ba, float o[4]) {
    float ct[4];
    #pragma unroll
    for (int r = 0; r < 4; ++r) {
        float v = ba[r];
        #pragma unroll
        for (int k = 0; k < 5; ++k) v += W[r * 5 + k] * cb[k];
        ct[r] = cosf(v);
    }
    o[1] = ct[0] * ct[1];
    o[2] = o[1] * ct[2];
    o[3] = o[2] * ct[3];
    o[0] = ct[1] * ct[2] * ct[3];
}

__global__ __launch_bounds__(64) void qlstm_kernel(
    const float* __restrict__ qc,   // d_out[0..2047]: qcnn_out, layout b*128+t
    const float* __restrict__ thf, const float* __restrict__ thi,
    const float* __restrict__ thg, const float* __restrict__ tho,
    const float* __restrict__ Wf, const float* __restrict__ bf,
    const float* __restrict__ Wi, const float* __restrict__ bi,
    const float* __restrict__ Wg, const float* __restrict__ bg,
    const float* __restrict__ Wo, const float* __restrict__ bo,
    const float* __restrict__ Wh, const float* __restrict__ bh,
    float* __restrict__ out) {
    __shared__ float q[2048];   // transposed: q[t*16 + b] (conflict-free reads)
    for (int i = threadIdx.x; i < 2048; i += 64) {
        int b = i >> 7, t = i & 127;
        q[t * 16 + b] = qc[i];
    }
    __syncthreads();

    int b = threadIdx.x;
    if (b >= 16) return;

    float wF[20], wI[20], wG[20], wO[20];
    float aF[4], aI[4], aG[4], aO[4];   // bias + theta folded
    #pragma unroll
    for (int k = 0; k < 20; ++k) { wF[k] = Wf[k]; wI[k] = Wi[k]; wG[k] = Wg[k]; wO[k] = Wo[k]; }
    #pragma unroll
    for (int r = 0; r < 4; ++r) {
        aF[r] = bf[r] + thf[r];
        aI[r] = bi[r] + thi[r];
        aG[r] = bg[r] + thg[r];
        aO[r] = bo[r] + tho[r];
    }

    float h[4] = {0.f, 0.f, 0.f, 0.f};
    float c[4] = {0.f, 0.f, 0.f, 0.f};
    for (int t = 0; t < 128; ++t) {
        float cb[5] = {q[t * 16 + b], h[0], h[1], h[2], h[3]};
        float fo[4], io[4], go[4], oo[4];
        qgate4(cb, wF, aF, fo);
        qgate4(cb, wI, aI, io);
        qgate4(cb, wG, aG, go);
        qgate4(cb, wO, aO, oo);
        #pragma unroll
        for (int r = 0; r < 4; ++r) {
            float fr = sigf(fo[r]);
            float ir = sigf(io[r]);
            float gr = tanhf(go[r]);
            float orr = sigf(oo[r]);
            c[r] = fr * c[r] + ir * gr;
            h[r] = orr * tanhf(c[r]);
        }
    }
    out[2048 + b] = bh[0] + Wh[0] * h[0] + Wh[1] * h[1] + Wh[2] * h[2] + Wh[3] * h[3];
}

extern "C" void kernel_launch(void* const* d_in, const int* in_sizes, int n_in,
                              void* d_out, int out_size, void* d_ws, size_t ws_size,
                              hipStream_t stream) {
    const float* x = (const float*)d_in[0];
    const float* w = (const float*)d_in[1];
    float* out = (float*)d_out;

    qcnn_kernel<<<2048, 128, 0, stream>>>(x, w, out);
    qlstm_kernel<<<1, 64, 0, stream>>>(
        out,
        (const float*)d_in[2], (const float*)d_in[3],
        (const float*)d_in[4], (const float*)d_in[5],
        (const float*)d_in[6], (const float*)d_in[7],
        (const float*)d_in[8], (const float*)d_in[9],
        (const float*)d_in[10], (const float*)d_in[11],
        (const float*)d_in[12], (const float*)d_in[13],
        (const float*)d_in[14], (const float*)d_in[15],
        out);
}

// Round 2
// 150.236 us; speedup vs baseline: 3.2384x; 3.2384x over previous
//
#include <hip/hip_runtime.h>
#include <math.h>

#define PI_F 3.14159265358979323846f

__device__ __forceinline__ void wbar() { __builtin_amdgcn_wave_barrier(); }
__device__ __forceinline__ float rcpf(float x) { return __builtin_amdgcn_rcpf(x); }

// ---------------------------------------------------------------------------
// QCNN: one block = ONE WAVE (64 threads) per sample, 8-qubit state (256 c64)
// in LDS. Qubit q -> bit (7-q) of the flat index. Wave-synchronous: LDS ops
// within a single wave execute in program order -> no __syncthreads needed.
// wbar() prevents compiler reordering (zero HW cost).
// ---------------------------------------------------------------------------

// general 2x2 gate: 128 pairs, 2 per lane (all 256 indices disjoint)
__device__ __forceinline__ void ap1g(float2* st, int q,
                                     float2 u00, float2 u01,
                                     float2 u10, float2 u11) {
    int p = 7 - q, m = 1 << p;
    int tA = threadIdx.x, tB = tA + 64;
    int iA = ((tA >> p) << (p + 1)) | (tA & (m - 1)), jA = iA | m;
    int iB = ((tB >> p) << (p + 1)) | (tB & (m - 1)), jB = iB | m;
    float2 aA = st[iA], bA = st[jA], aB = st[iB], bB = st[jB];
    float2 r0A = make_float2(u00.x*aA.x - u00.y*aA.y + u01.x*bA.x - u01.y*bA.y,
                             u00.x*aA.y + u00.y*aA.x + u01.x*bA.y + u01.y*bA.x);
    float2 r1A = make_float2(u10.x*aA.x - u10.y*aA.y + u11.x*bA.x - u11.y*bA.y,
                             u10.x*aA.y + u10.y*aA.x + u11.x*bA.y + u11.y*bA.x);
    float2 r0B = make_float2(u00.x*aB.x - u00.y*aB.y + u01.x*bB.x - u01.y*bB.y,
                             u00.x*aB.y + u00.y*aB.x + u01.x*bB.y + u01.y*bB.x);
    float2 r1B = make_float2(u10.x*aB.x - u10.y*aB.y + u11.x*bB.x - u11.y*bB.y,
                             u10.x*aB.y + u10.y*aB.x + u11.x*bB.y + u11.y*bB.x);
    st[iA] = r0A; st[jA] = r1A; st[iB] = r0B; st[jB] = r1B;
    wbar();
}

// diagonal gate diag(d0, d1)  (RZ, phase)
__device__ __forceinline__ void ap1diag(float2* st, int q, float2 d0, float2 d1) {
    int p = 7 - q, m = 1 << p;
    int tA = threadIdx.x, tB = tA + 64;
    int iA = ((tA >> p) << (p + 1)) | (tA & (m - 1)), jA = iA | m;
    int iB = ((tB >> p) << (p + 1)) | (tB & (m - 1)), jB = iB | m;
    float2 aA = st[iA], bA = st[jA], aB = st[iB], bB = st[jB];
    st[iA] = make_float2(d0.x*aA.x - d0.y*aA.y, d0.x*aA.y + d0.y*aA.x);
    st[jA] = make_float2(d1.x*bA.x - d1.y*bA.y, d1.x*bA.y + d1.y*bA.x);
    st[iB] = make_float2(d0.x*aB.x - d0.y*aB.y, d0.x*aB.y + d0.y*aB.x);
    st[jB] = make_float2(d1.x*bB.x - d1.y*bB.y, d1.x*bB.y + d1.y*bB.x);
    wbar();
}

// real rotation [[c,-s],[s,c]]  (RY)
__device__ __forceinline__ void ap1real(float2* st, int q, float c, float s) {
    int p = 7 - q, m = 1 << p;
    int tA = threadIdx.x, tB = tA + 64;
    int iA = ((tA >> p) << (p + 1)) | (tA & (m - 1)), jA = iA | m;
    int iB = ((tB >> p) << (p + 1)) | (tB & (m - 1)), jB = iB | m;
    float2 aA = st[iA], bA = st[jA], aB = st[iB], bB = st[jB];
    st[iA] = make_float2(c*aA.x - s*bA.x, c*aA.y - s*bA.y);
    st[jA] = make_float2(s*aA.x + c*bA.x, s*aA.y + c*bA.y);
    st[iB] = make_float2(c*aB.x - s*bB.x, c*aB.y - s*bB.y);
    st[jB] = make_float2(s*aB.x + c*bB.x, s*aB.y + c*bB.y);
    wbar();
}

__device__ __forceinline__ void aprz(float2* st, int q, float t) {
    float c = __cosf(0.5f * t), s = __sinf(0.5f * t);
    ap1diag(st, q, make_float2(c, -s), make_float2(c, s));
}

__device__ __forceinline__ void apry(float2* st, int q, float t) {
    ap1real(st, q, __cosf(0.5f * t), __sinf(0.5f * t));
}

// CNOT control qc, target qt: 64 swap pairs, 1 per lane
__device__ __forceinline__ void apcx(float2* st, int qc, int qt) {
    int pc = 7 - qc, pt = 7 - qt;
    int lo = pc < pt ? pc : pt;
    int hi = pc < pt ? pt : pc;
    int v = threadIdx.x;
    v = ((v >> lo) << (lo + 1)) | (v & ((1 << lo) - 1));
    v = ((v >> hi) << (hi + 1)) | (v & ((1 << hi) - 1));
    int i = v | (1 << pc);
    int j = i | (1 << pt);
    float2 tmp = st[i];
    st[i] = st[j];
    st[j] = tmp;
    wbar();
}

__device__ void conv_blk(float2* st, const float* __restrict__ p, int q1, int q2) {
    aprz(st, q2, -0.5f * PI_F);
    apcx(st, q2, q1);
    aprz(st, q1, p[0]);
    apry(st, q2, p[1]);
    apcx(st, q1, q2);
    apry(st, q2, p[2]);
    apcx(st, q2, q1);
    aprz(st, q1, 0.5f * PI_F);
}

__device__ void pool_blk(float2* st, const float* __restrict__ p, int src, int sink) {
    aprz(st, sink, -0.5f * PI_F);
    apcx(st, sink, src);
    aprz(st, src, p[0]);
    apry(st, sink, p[1]);
    apcx(st, src, sink);
    apry(st, sink, p[2]);
}

__global__ __launch_bounds__(64) void qcnn_kernel(const float* __restrict__ x,
                                                  const float* __restrict__ w,
                                                  float* __restrict__ out) {
    __shared__ float2 st[256];
    int n = blockIdx.x;
    int tid = threadIdx.x;

    st[tid]       = make_float2(0.f, 0.f);
    st[tid + 64]  = make_float2(0.f, 0.f);
    st[tid + 128] = make_float2(0.f, 0.f);
    st[tid + 192] = make_float2(0.f, 0.f);
    if (tid == 0) st[0] = make_float2(1.f, 0.f);
    wbar();

    // Fused ZFeatureMap reps=2: per qubit U = P(2x)·H·P(2x)·H
    const float* xr = x + n * 8;
    #pragma unroll
    for (int q = 0; q < 8; ++q) {
        float phi = 2.0f * xr[q];
        float e1x = __cosf(phi), e1y = __sinf(phi);
        float e2x = e1x * e1x - e1y * e1y;   // e^{2i phi}
        float e2y = 2.0f * e1x * e1y;
        float2 u00 = make_float2(0.5f * (1.0f + e1x), 0.5f * e1y);
        float2 u01 = make_float2(0.5f * (1.0f - e1x), -0.5f * e1y);
        float2 u10 = make_float2(0.5f * (e1x - e2x), 0.5f * (e1y - e2y));
        float2 u11 = make_float2(0.5f * (e1x + e2x), 0.5f * (e1y + e2y));
        ap1g(st, q, u00, u01, u10, u11);
    }

    conv_blk(st, w + 0, 0, 1);
    conv_blk(st, w + 3, 2, 3);
    conv_blk(st, w + 6, 4, 5);
    conv_blk(st, w + 9, 6, 7);
    pool_blk(st, w + 12, 0, 1);
    pool_blk(st, w + 15, 2, 3);
    pool_blk(st, w + 18, 4, 5);
    pool_blk(st, w + 21, 6, 7);
    conv_blk(st, w + 24, 0, 1);
    conv_blk(st, w + 27, 2, 3);
    pool_blk(st, w + 30, 0, 1);
    pool_blk(st, w + 33, 2, 3);
    conv_blk(st, w + 36, 0, 1);
    pool_blk(st, w + 39, 0, 1);

    // <Z_7>: qubit 7 = LSB of flat index; lane owns amps 4t..4t+3
    float2 v0 = st[4 * tid], v1 = st[4 * tid + 1];
    float2 v2 = st[4 * tid + 2], v3 = st[4 * tid + 3];
    float part = (v0.x*v0.x + v0.y*v0.y) - (v1.x*v1.x + v1.y*v1.y)
               + (v2.x*v2.x + v2.y*v2.y) - (v3.x*v3.x + v3.y*v3.y);
    #pragma unroll
    for (int off = 32; off > 0; off >>= 1)
        part += __shfl_down(part, off, 64);
    if (tid == 0) out[n] = part;
}

// ---------------------------------------------------------------------------
// QLSTM closed-form qgate: a_i = v_i + theta_i, c_i = cos(a_i):
//   out = [c1*c2*c3, c0*c1, c0*c1*c2, c0*c1*c2*c3]
// lane = b*4 + g (b=batch 0..15, g=gate: 0=f,1=i,2=g(tanh),3=o).
// Each lane: 4 dots + 4 native cos + unified nonlinearity; cross-gate
// exchange via shfl_xor (quad transpose); c,h kept redundantly per lane.
// ---------------------------------------------------------------------------

__device__ __forceinline__ float fast_tanh(float x) {
    float E = __expf(2.0f * x);
    return (E - 1.0f) * rcpf(E + 1.0f);
}

__device__ __forceinline__ float pick(int m, float a0, float a1, float a2, float a3) {
    float r = a3;
    r = (m == 2) ? a2 : r;
    r = (m == 1) ? a1 : r;
    r = (m == 0) ? a0 : r;
    return r;
}

__global__ __launch_bounds__(64) void qlstm_kernel(
    const float* __restrict__ qc,   // d_out[0..2047]: qcnn_out, layout b*128+t
    const float* __restrict__ thf, const float* __restrict__ thi,
    const float* __restrict__ thg, const float* __restrict__ tho,
    const float* __restrict__ Wf, const float* __restrict__ bf,
    const float* __restrict__ Wi, const float* __restrict__ bi,
    const float* __restrict__ Wg, const float* __restrict__ bg,
    const float* __restrict__ Wo, const float* __restrict__ bo,
    const float* __restrict__ Wh, const float* __restrict__ bh,
    float* __restrict__ out) {
    __shared__ float qsh[2048];     // transposed: qsh[t*16+b] -> quad-broadcast reads
    int lane = threadIdx.x;

    const float4* qc4 = (const float4*)qc;
    #pragma unroll
    for (int i0 = 0; i0 < 512; i0 += 64) {
        int i = i0 + lane;
        float4 v = qc4[i];
        int b = i >> 5;             // element 4i: b = 4i/128
        int t = (i & 31) << 2;
        qsh[t * 16 + b]       = v.x;
        qsh[(t + 1) * 16 + b] = v.y;
        qsh[(t + 2) * 16 + b] = v.z;
        qsh[(t + 3) * 16 + b] = v.w;
    }
    wbar();                          // single wave: LDS ops are program-ordered

    int b = lane >> 2, g = lane & 3;
    const float* Wp = (g == 0) ? Wf : (g == 1) ? Wi : (g == 2) ? Wg : Wo;
    const float* bp = (g == 0) ? bf : (g == 1) ? bi : (g == 2) ? bg : bo;
    const float* tp = (g == 0) ? thf : (g == 1) ? thi : (g == 2) ? thg : tho;

    float W[20], a[4];
    #pragma unroll
    for (int k = 0; k < 20; ++k) W[k] = Wp[k];
    #pragma unroll
    for (int r = 0; r < 4; ++r) a[r] = bp[r] + tp[r];

    bool isG = (g == 2);
    float es = isG ? 2.0f : -1.0f;   // sig(x)=1/(1+e^{-x}); tanh(x)=(e^{2x}-1)/(e^{2x}+1)
    int mF = g, mI = g ^ 1, mG = g ^ 2, mO = g ^ 3;

    float c0 = 0.f, c1 = 0.f, c2 = 0.f, c3 = 0.f;
    float h0 = 0.f, h1 = 0.f, h2 = 0.f, h3 = 0.f;

    for (int t = 0; t < 128; ++t) {
        float xv = qsh[t * 16 + b];
        float vA = a[0] + W[0]*xv + W[1]*h0 + W[2]*h1 + W[3]*h2 + W[4]*h3;
        float vB = a[1] + W[5]*xv + W[6]*h0 + W[7]*h1 + W[8]*h2 + W[9]*h3;
        float vC = a[2] + W[10]*xv + W[11]*h0 + W[12]*h1 + W[13]*h2 + W[14]*h3;
        float vD = a[3] + W[15]*xv + W[16]*h0 + W[17]*h1 + W[18]*h2 + W[19]*h3;
        float cA = __cosf(vA), cB = __cosf(vB), cC = __cosf(vC), cD = __cosf(vD);
        // parity products: rows [c1c2c3, c0c1, c0c1c2, c0c1c2c3]
        float rB = cA * cB, rC = rB * cC, rD = rC * cD, rA = cB * cC * cD;
        // unified nonlinearity: num * rcp(E+1); E=e^{-x} (sig) or e^{2x} (tanh)
        float EA = __expf(es * rA), EB = __expf(es * rB);
        float EC = __expf(es * rC), ED = __expf(es * rD);
        float nA = (isG ? EA - 1.0f : 1.0f) * rcpf(EA + 1.0f);
        float nB = (isG ? EB - 1.0f : 1.0f) * rcpf(EB + 1.0f);
        float nC = (isG ? EC - 1.0f : 1.0f) * rcpf(EC + 1.0f);
        float nD = (isG ? ED - 1.0f : 1.0f) * rcpf(ED + 1.0f);
        // quad transpose: A[j] = value from lane g^j
        float a1A = __shfl_xor(nA, 1, 64), a2A = __shfl_xor(nA, 2, 64), a3A = __shfl_xor(nA, 3, 64);
        float a1B = __shfl_xor(nB, 1, 64), a2B = __shfl_xor(nB, 2, 64), a3B = __shfl_xor(nB, 3, 64);
        float a1C = __shfl_xor(nC, 1, 64), a2C = __shfl_xor(nC, 2, 64), a3C = __shfl_xor(nC, 3, 64);
        float a1D = __shfl_xor(nD, 1, 64), a2D = __shfl_xor(nD, 2, 64), a3D = __shfl_xor(nD, 3, 64);
        // gate g' lives at A[g ^ g']
        float FA = pick(mF, nA, a1A, a2A, a3A), IA = pick(mI, nA, a1A, a2A, a3A);
        float GA = pick(mG, nA, a1A, a2A, a3A), OA = pick(mO, nA, a1A, a2A, a3A);
        float FB = pick(mF, nB, a1B, a2B, a3B), IB = pick(mI, nB, a1B, a2B, a3B);
        float GB = pick(mG, nB, a1B, a2B, a3B), OB = pick(mO, nB, a1B, a2B, a3B);
        float FC = pick(mF, nC, a1C, a2C, a3C), IC = pick(mI, nC, a1C, a2C, a3C);
        float GC = pick(mG, nC, a1C, a2C, a3C), OC = pick(mO, nC, a1C, a2C, a3C);
        float FD = pick(mF, nD, a1D, a2D, a3D), ID = pick(mI, nD, a1D, a2D, a3D);
        float GD = pick(mG, nD, a1D, a2D, a3D), OD = pick(mO, nD, a1D, a2D, a3D);
        c0 = FA * c0 + IA * GA;  h0 = OA * fast_tanh(c0);
        c1 = FB * c1 + IB * GB;  h1 = OB * fast_tanh(c1);
        c2 = FC * c2 + IC * GC;  h2 = OC * fast_tanh(c2);
        c3 = FD * c3 + ID * GD;  h3 = OD * fast_tanh(c3);
    }

    if (g == 0)
        out[2048 + b] = bh[0] + Wh[0]*h0 + Wh[1]*h1 + Wh[2]*h2 + Wh[3]*h3;
}

extern "C" void kernel_launch(void* const* d_in, const int* in_sizes, int n_in,
                              void* d_out, int out_size, void* d_ws, size_t ws_size,
                              hipStream_t stream) {
    const float* x = (const float*)d_in[0];
    const float* w = (const float*)d_in[1];
    float* out = (float*)d_out;

    qcnn_kernel<<<2048, 64, 0, stream>>>(x, w, out);
    qlstm_kernel<<<1, 64, 0, stream>>>(
        out,
        (const float*)d_in[2], (const float*)d_in[3],
        (const float*)d_in[4], (const float*)d_in[5],
        (const float*)d_in[6], (const float*)d_in[7],
        (const float*)d_in[8], (const float*)d_in[9],
        (const float*)d_in[10], (const float*)d_in[11],
        (const float*)d_in[12], (const float*)d_in[13],
        (const float*)d_in[14], (const float*)d_in[15],
        out);
}

// Round 3
// 127.021 us; speedup vs baseline: 3.8303x; 1.1828x over previous
//
#include <hip/hip_runtime.h>
#include <math.h>

#define PI_F 3.14159265358979323846f

__device__ __forceinline__ float rcpf(float x) { return __builtin_amdgcn_rcpf(x); }
__device__ __forceinline__ void fswap(float2& p, float2& q) { float2 t = p; p = q; q = t; }

// ---------------------------------------------------------------------------
// QCNN: one wave per sample, 256-amp state in REGISTERS (4 float2/lane).
// Amp index mapping: qubit0 -> reg bit1, qubit1 -> reg bit0,
// qubit q in 2..7 -> lane bit (q-2).
// Exchanges: q2,q3 via DPP quad_perm (VALU); q4,q5,q6 via ds_swizzle;
// q7 via shfl_xor(32). Diagonal gates (RZ/P) need no exchange at all.
// ---------------------------------------------------------------------------

template<int Q>
__device__ __forceinline__ float exq(float v) {
    if constexpr (Q == 2)        // lane^1: quad_perm [1,0,3,2]
        return __int_as_float(__builtin_amdgcn_update_dpp(0, __float_as_int(v), 0xB1, 0xF, 0xF, true));
    else if constexpr (Q == 3)   // lane^2: quad_perm [2,3,0,1]
        return __int_as_float(__builtin_amdgcn_update_dpp(0, __float_as_int(v), 0x4E, 0xF, 0xF, true));
    else if constexpr (Q == 4)   // lane^4
        return __int_as_float(__builtin_amdgcn_ds_swizzle(__float_as_int(v), 0x101F));
    else if constexpr (Q == 5)   // lane^8
        return __int_as_float(__builtin_amdgcn_ds_swizzle(__float_as_int(v), 0x201F));
    else if constexpr (Q == 6)   // lane^16
        return __int_as_float(__builtin_amdgcn_ds_swizzle(__float_as_int(v), 0x401F));
    else                         // lane^32
        return __shfl_xor(v, 32, 64);
}

// RZ(q,th) = diag(e^{-i th/2}, e^{+i th/2}) — diagonal: no exchange.
template<int Q>
__device__ __forceinline__ void rzg(float2 a[4], float th, int lane) {
    float c = __cosf(0.5f * th), s = __sinf(0.5f * th);
    if constexpr (Q >= 2) {
        float se = ((lane >> (Q - 2)) & 1) ? s : -s;
        #pragma unroll
        for (int r = 0; r < 4; ++r) {
            float nx = c * a[r].x - se * a[r].y;
            float ny = c * a[r].y + se * a[r].x;
            a[r] = make_float2(nx, ny);
        }
    } else {
        #pragma unroll
        for (int r = 0; r < 4; ++r) {
            int bit = (Q == 0) ? (r >> 1) : (r & 1);
            float se = bit ? s : -s;
            float nx = c * a[r].x - se * a[r].y;
            float ny = c * a[r].y + se * a[r].x;
            a[r] = make_float2(nx, ny);
        }
    }
}

// RY(q,th) = [[c,-s],[s,c]], c=cos(th/2), s=sin(th/2)
template<int Q>
__device__ __forceinline__ void ryg(float2 a[4], float th, int lane) {
    float c = __cosf(0.5f * th), s = __sinf(0.5f * th);
    if constexpr (Q >= 2) {
        float se = ((lane >> (Q - 2)) & 1) ? s : -s;   // bit0: c*own - s*oth; bit1: c*own + s*oth
        #pragma unroll
        for (int r = 0; r < 4; ++r) {
            float ox = exq<Q>(a[r].x), oy = exq<Q>(a[r].y);
            a[r] = make_float2(c * a[r].x + se * ox, c * a[r].y + se * oy);
        }
    } else if constexpr (Q == 0) {   // pairs (a0,a2),(a1,a3)
        #pragma unroll
        for (int r = 0; r < 2; ++r) {
            float2 lo = a[r], hi = a[r + 2];
            a[r]     = make_float2(c * lo.x - s * hi.x, c * lo.y - s * hi.y);
            a[r + 2] = make_float2(s * lo.x + c * hi.x, s * lo.y + c * hi.y);
        }
    } else {                          // pairs (a0,a1),(a2,a3)
        #pragma unroll
        for (int r = 0; r < 4; r += 2) {
            float2 lo = a[r], hi = a[r + 1];
            a[r]     = make_float2(c * lo.x - s * hi.x, c * lo.y - s * hi.y);
            a[r + 1] = make_float2(s * lo.x + c * hi.x, s * lo.y + c * hi.y);
        }
    }
}

// CX(C,T): flip T where C==1. Only (0,1)-in-lane and both-cross occur.
template<int C, int T>
__device__ __forceinline__ void cxg(float2 a[4], int lane) {
    if constexpr (C >= 2) {
        bool cb = (lane >> (C - 2)) & 1;
        #pragma unroll
        for (int r = 0; r < 4; ++r) {
            float ox = exq<T>(a[r].x), oy = exq<T>(a[r].y);
            a[r].x = cb ? ox : a[r].x;
            a[r].y = cb ? oy : a[r].y;
        }
    } else if constexpr (C == 0 && T == 1) {
        fswap(a[2], a[3]);   // q0=1 regs: flip q1 bit
    } else {                  // C==1, T==0
        fswap(a[1], a[3]);   // q1=1 regs: flip q0 bit
    }
}

// Fused ZFeatureMap gate U = P(2x)·H·P(2x)·H (general 2x2)
template<int Q>
__device__ __forceinline__ void featg(float2 a[4], float xq, int lane) {
    float phi = 2.0f * xq;
    float e1x = __cosf(phi), e1y = __sinf(phi);
    float e2x = e1x * e1x - e1y * e1y;
    float e2y = 2.0f * e1x * e1y;
    float2 u00 = make_float2(0.5f * (1.0f + e1x),  0.5f * e1y);
    float2 u01 = make_float2(0.5f * (1.0f - e1x), -0.5f * e1y);
    float2 u10 = make_float2(0.5f * (e1x - e2x), 0.5f * (e1y - e2y));
    float2 u11 = make_float2(0.5f * (e1x + e2x), 0.5f * (e1y + e2y));
    if constexpr (Q >= 2) {
        bool bset = (lane >> (Q - 2)) & 1;
        float csx = bset ? u11.x : u00.x, csy = bset ? u11.y : u00.y;  // coeff on own
        float cox = bset ? u10.x : u01.x, coy = bset ? u10.y : u01.y;  // coeff on other
        #pragma unroll
        for (int r = 0; r < 4; ++r) {
            float ox = exq<Q>(a[r].x), oy = exq<Q>(a[r].y);
            float nx = csx * a[r].x - csy * a[r].y + cox * ox - coy * oy;
            float ny = csx * a[r].y + csy * a[r].x + cox * oy + coy * ox;
            a[r] = make_float2(nx, ny);
        }
    } else {
        float2 l, h;
        #define APPL(LO, HI)                                                        \
            l = a[LO]; h = a[HI];                                                   \
            a[LO] = make_float2(u00.x*l.x - u00.y*l.y + u01.x*h.x - u01.y*h.y,      \
                                u00.x*l.y + u00.y*l.x + u01.x*h.y + u01.y*h.x);     \
            a[HI] = make_float2(u10.x*l.x - u10.y*l.y + u11.x*h.x - u11.y*h.y,      \
                                u10.x*l.y + u10.y*l.x + u11.x*h.y + u11.y*h.x);
        if constexpr (Q == 0) { APPL(0, 2) APPL(1, 3) }
        else                  { APPL(0, 1) APPL(2, 3) }
        #undef APPL
    }
}

template<int Q1, int Q2>
__device__ __forceinline__ void convg(float2 a[4], const float* __restrict__ p, int lane) {
    rzg<Q2>(a, -0.5f * PI_F, lane);
    cxg<Q2, Q1>(a, lane);
    rzg<Q1>(a, p[0], lane);
    ryg<Q2>(a, p[1], lane);
    cxg<Q1, Q2>(a, lane);
    ryg<Q2>(a, p[2], lane);
    cxg<Q2, Q1>(a, lane);
    rzg<Q1>(a, 0.5f * PI_F, lane);
}

template<int Q1, int Q2>
__device__ __forceinline__ void poolg(float2 a[4], const float* __restrict__ p, int lane) {
    rzg<Q2>(a, -0.5f * PI_F, lane);
    cxg<Q2, Q1>(a, lane);
    rzg<Q1>(a, p[0], lane);
    ryg<Q2>(a, p[1], lane);
    cxg<Q1, Q2>(a, lane);
    ryg<Q2>(a, p[2], lane);
}

__global__ __launch_bounds__(64) void qcnn_kernel(const float* __restrict__ x,
                                                  const float* __restrict__ w,
                                                  float* __restrict__ out) {
    int n = blockIdx.x;
    int lane = threadIdx.x;
    float2 a[4];
    a[0] = make_float2(lane == 0 ? 1.0f : 0.0f, 0.0f);
    a[1] = make_float2(0.0f, 0.0f);
    a[2] = make_float2(0.0f, 0.0f);
    a[3] = make_float2(0.0f, 0.0f);

    const float* xr = x + n * 8;
    featg<0>(a, xr[0], lane);
    featg<1>(a, xr[1], lane);
    featg<2>(a, xr[2], lane);
    featg<3>(a, xr[3], lane);
    featg<4>(a, xr[4], lane);
    featg<5>(a, xr[5], lane);
    featg<6>(a, xr[6], lane);
    featg<7>(a, xr[7], lane);

    convg<0,1>(a, w + 0,  lane);
    convg<2,3>(a, w + 3,  lane);
    convg<4,5>(a, w + 6,  lane);
    convg<6,7>(a, w + 9,  lane);
    poolg<0,1>(a, w + 12, lane);
    poolg<2,3>(a, w + 15, lane);
    poolg<4,5>(a, w + 18, lane);
    poolg<6,7>(a, w + 21, lane);
    convg<0,1>(a, w + 24, lane);
    convg<2,3>(a, w + 27, lane);
    poolg<0,1>(a, w + 30, lane);
    poolg<2,3>(a, w + 33, lane);
    convg<0,1>(a, w + 36, lane);
    poolg<0,1>(a, w + 39, lane);

    // <Z_q7>: q7 = lane bit5
    float ssum = 0.f;
    #pragma unroll
    for (int r = 0; r < 4; ++r)
        ssum += a[r].x * a[r].x + a[r].y * a[r].y;
    ssum = (lane & 32) ? -ssum : ssum;
    #pragma unroll
    for (int m = 1; m < 64; m <<= 1)
        ssum += __shfl_xor(ssum, m, 64);
    if (lane == 0) out[n] = ssum;
}

// ---------------------------------------------------------------------------
// QLSTM closed-form qgate (verified): c_i = cos(v_i + th_i):
//   out = [c1c2c3, c0c1, c0c1c2, c0c1c2c3]
// lane = b*4+g. Cross-gate F/I/G/O via DPP quad broadcasts (no picks).
// ---------------------------------------------------------------------------

template<int CTRL>
__device__ __forceinline__ float bq(float v) {   // quad_perm broadcast
    return __int_as_float(__builtin_amdgcn_update_dpp(0, __float_as_int(v), CTRL, 0xF, 0xF, true));
}

__global__ __launch_bounds__(64) void qlstm_kernel(
    const float* __restrict__ qc,
    const float* __restrict__ thf, const float* __restrict__ thi,
    const float* __restrict__ thg, const float* __restrict__ tho,
    const float* __restrict__ Wf, const float* __restrict__ bf,
    const float* __restrict__ Wi, const float* __restrict__ bi,
    const float* __restrict__ Wg, const float* __restrict__ bg,
    const float* __restrict__ Wo, const float* __restrict__ bo,
    const float* __restrict__ Wh, const float* __restrict__ bh,
    float* __restrict__ out) {
    __shared__ __align__(16) float qsh[16 * 132];   // row stride 132: reads 2-way max
    int lane = threadIdx.x;

    const float4* qc4 = (const float4*)qc;
    #pragma unroll
    for (int k = 0; k < 8; ++k) {
        int i = k * 64 + lane;          // 512 float4 total
        float4 v = qc4[i];
        int b = i >> 5;                 // 32 float4 per batch row
        int t = (i & 31) << 2;
        *(float4*)&qsh[b * 132 + t] = v;  // conflict-free (consecutive lanes contiguous)
    }
    __builtin_amdgcn_wave_barrier();     // single wave: LDS ops program-ordered

    int b = lane >> 2, g = lane & 3;
    const float* Wp = (g == 0) ? Wf : (g == 1) ? Wi : (g == 2) ? Wg : Wo;
    const float* bp = (g == 0) ? bf : (g == 1) ? bi : (g == 2) ? bg : bo;
    const float* tp = (g == 0) ? thf : (g == 1) ? thi : (g == 2) ? thg : tho;

    float W[20], av[4];
    #pragma unroll
    for (int k = 0; k < 20; ++k) W[k] = Wp[k];
    #pragma unroll
    for (int r = 0; r < 4; ++r) av[r] = bp[r] + tp[r];

    bool isG = (g == 2);
    float es = isG ? 2.0f : -1.0f;  // sig: E=e^{-x}, n=1/(E+1); tanh: E=e^{2x}, n=(E-1)/(E+1)

    float c0 = 0.f, c1 = 0.f, c2 = 0.f, c3 = 0.f;
    float h0 = 0.f, h1 = 0.f, h2 = 0.f, h3 = 0.f;
    const float* qrow = &qsh[b * 132];

    for (int t = 0; t < 128; ++t) {
        float xv = qrow[t];
        float vA = av[0] + W[0]*xv  + W[1]*h0  + W[2]*h1  + W[3]*h2  + W[4]*h3;
        float vB = av[1] + W[5]*xv  + W[6]*h0  + W[7]*h1  + W[8]*h2  + W[9]*h3;
        float vC = av[2] + W[10]*xv + W[11]*h0 + W[12]*h1 + W[13]*h2 + W[14]*h3;
        float vD = av[3] + W[15]*xv + W[16]*h0 + W[17]*h1 + W[18]*h2 + W[19]*h3;
        float cA = __cosf(vA), cB = __cosf(vB), cC = __cosf(vC), cD = __cosf(vD);
        float rB = cA * cB, rC = rB * cC, rD = rC * cD, rA = cB * (cC * cD);
        float EA = __expf(es * rA), EB = __expf(es * rB);
        float EC = __expf(es * rC), ED = __expf(es * rD);
        float nA = (isG ? EA - 1.0f : 1.0f) * rcpf(EA + 1.0f);
        float nB = (isG ? EB - 1.0f : 1.0f) * rcpf(EB + 1.0f);
        float nC = (isG ? EC - 1.0f : 1.0f) * rcpf(EC + 1.0f);
        float nD = (isG ? ED - 1.0f : 1.0f) * rcpf(ED + 1.0f);
        // F/I/G/O per row via quad broadcasts (g=0..3 live at quad slots 0..3)
        float FA = bq<0x00>(nA), IA = bq<0x55>(nA), GA = bq<0xAA>(nA), OA = bq<0xFF>(nA);
        float FB = bq<0x00>(nB), IB = bq<0x55>(nB), GB = bq<0xAA>(nB), OB = bq<0xFF>(nB);
        float FC = bq<0x00>(nC), IC = bq<0x55>(nC), GC = bq<0xAA>(nC), OC = bq<0xFF>(nC);
        float FD = bq<0x00>(nD), ID = bq<0x55>(nD), GD = bq<0xAA>(nD), OD = bq<0xFF>(nD);
        c0 = FA * c0 + IA * GA;
        c1 = FB * c1 + IB * GB;
        c2 = FC * c2 + IC * GC;
        c3 = FD * c3 + ID * GD;
        float E0 = __expf(2.0f * c0), E1 = __expf(2.0f * c1);
        float E2 = __expf(2.0f * c2), E3 = __expf(2.0f * c3);
        h0 = OA * (E0 - 1.0f) * rcpf(E0 + 1.0f);
        h1 = OB * (E1 - 1.0f) * rcpf(E1 + 1.0f);
        h2 = OC * (E2 - 1.0f) * rcpf(E2 + 1.0f);
        h3 = OD * (E3 - 1.0f) * rcpf(E3 + 1.0f);
    }

    if (g == 0)
        out[2048 + b] = bh[0] + Wh[0]*h0 + Wh[1]*h1 + Wh[2]*h2 + Wh[3]*h3;
}

extern "C" void kernel_launch(void* const* d_in, const int* in_sizes, int n_in,
                              void* d_out, int out_size, void* d_ws, size_t ws_size,
                              hipStream_t stream) {
    const float* x = (const float*)d_in[0];
    const float* w = (const float*)d_in[1];
    float* out = (float*)d_out;

    qcnn_kernel<<<2048, 64, 0, stream>>>(x, w, out);
    qlstm_kernel<<<1, 64, 0, stream>>>(
        out,
        (const float*)d_in[2], (const float*)d_in[3],
        (const float*)d_in[4], (const float*)d_in[5],
        (const float*)d_in[6], (const float*)d_in[7],
        (const float*)d_in[8], (const float*)d_in[9],
        (const float*)d_in[10], (const float*)d_in[11],
        (const float*)d_in[12], (const float*)d_in[13],
        (const float*)d_in[14], (const float*)d_in[15],
        out);
}

// Round 4
// 122.506 us; speedup vs baseline: 3.9714x; 1.0369x over previous
//
#include <hip/hip_runtime.h>
#include <math.h>

#define PI_F 3.14159265358979323846f

__device__ __forceinline__ float rcpf(float x) { return __builtin_amdgcn_rcpf(x); }
__device__ __forceinline__ void fswap(float2& p, float2& q) { float2 t = p; p = q; q = t; }

// ---------------------------------------------------------------------------
// QCNN: one wave per sample (4 samples per 256-thread block), 256-amp state
// in REGISTERS (4 float2/lane).
// Amp index mapping: qubit0 -> reg bit1, qubit1 -> reg bit0,
// qubit q in 2..7 -> lane bit (q-2).
// Exchanges: q2,q3 via DPP quad_perm (VALU); q4,q5,q6 via ds_swizzle;
// q7 via shfl_xor(32). Diagonal gates (RZ/P) need no exchange at all.
// ---------------------------------------------------------------------------

template<int Q>
__device__ __forceinline__ float exq(float v) {
    if constexpr (Q == 2)        // lane^1: quad_perm [1,0,3,2]
        return __int_as_float(__builtin_amdgcn_update_dpp(0, __float_as_int(v), 0xB1, 0xF, 0xF, true));
    else if constexpr (Q == 3)   // lane^2: quad_perm [2,3,0,1]
        return __int_as_float(__builtin_amdgcn_update_dpp(0, __float_as_int(v), 0x4E, 0xF, 0xF, true));
    else if constexpr (Q == 4)   // lane^4
        return __int_as_float(__builtin_amdgcn_ds_swizzle(__float_as_int(v), 0x101F));
    else if constexpr (Q == 5)   // lane^8
        return __int_as_float(__builtin_amdgcn_ds_swizzle(__float_as_int(v), 0x201F));
    else if constexpr (Q == 6)   // lane^16
        return __int_as_float(__builtin_amdgcn_ds_swizzle(__float_as_int(v), 0x401F));
    else                         // lane^32
        return __shfl_xor(v, 32, 64);
}

// RZ(q,th) = diag(e^{-i th/2}, e^{+i th/2}) — diagonal: no exchange.
template<int Q>
__device__ __forceinline__ void rzg(float2 a[4], float th, int lane) {
    float c = __cosf(0.5f * th), s = __sinf(0.5f * th);
    if constexpr (Q >= 2) {
        float se = ((lane >> (Q - 2)) & 1) ? s : -s;
        #pragma unroll
        for (int r = 0; r < 4; ++r) {
            float nx = c * a[r].x - se * a[r].y;
            float ny = c * a[r].y + se * a[r].x;
            a[r] = make_float2(nx, ny);
        }
    } else {
        #pragma unroll
        for (int r = 0; r < 4; ++r) {
            int bit = (Q == 0) ? (r >> 1) : (r & 1);
            float se = bit ? s : -s;
            float nx = c * a[r].x - se * a[r].y;
            float ny = c * a[r].y + se * a[r].x;
            a[r] = make_float2(nx, ny);
        }
    }
}

// RY(q,th) = [[c,-s],[s,c]], c=cos(th/2), s=sin(th/2)
template<int Q>
__device__ __forceinline__ void ryg(float2 a[4], float th, int lane) {
    float c = __cosf(0.5f * th), s = __sinf(0.5f * th);
    if constexpr (Q >= 2) {
        float se = ((lane >> (Q - 2)) & 1) ? s : -s;
        #pragma unroll
        for (int r = 0; r < 4; ++r) {
            float ox = exq<Q>(a[r].x), oy = exq<Q>(a[r].y);
            a[r] = make_float2(c * a[r].x + se * ox, c * a[r].y + se * oy);
        }
    } else if constexpr (Q == 0) {
        #pragma unroll
        for (int r = 0; r < 2; ++r) {
            float2 lo = a[r], hi = a[r + 2];
            a[r]     = make_float2(c * lo.x - s * hi.x, c * lo.y - s * hi.y);
            a[r + 2] = make_float2(s * lo.x + c * hi.x, s * lo.y + c * hi.y);
        }
    } else {
        #pragma unroll
        for (int r = 0; r < 4; r += 2) {
            float2 lo = a[r], hi = a[r + 1];
            a[r]     = make_float2(c * lo.x - s * hi.x, c * lo.y - s * hi.y);
            a[r + 1] = make_float2(s * lo.x + c * hi.x, s * lo.y + c * hi.y);
        }
    }
}

// CX(C,T): flip T where C==1.
template<int C, int T>
__device__ __forceinline__ void cxg(float2 a[4], int lane) {
    if constexpr (C >= 2) {
        bool cb = (lane >> (C - 2)) & 1;
        #pragma unroll
        for (int r = 0; r < 4; ++r) {
            float ox = exq<T>(a[r].x), oy = exq<T>(a[r].y);
            a[r].x = cb ? ox : a[r].x;
            a[r].y = cb ? oy : a[r].y;
        }
    } else if constexpr (C == 0 && T == 1) {
        fswap(a[2], a[3]);
    } else {
        fswap(a[1], a[3]);
    }
}

// Fused ZFeatureMap gate U = P(2x)·H·P(2x)·H (general 2x2)
template<int Q>
__device__ __forceinline__ void featg(float2 a[4], float xq, int lane) {
    float phi = 2.0f * xq;
    float e1x = __cosf(phi), e1y = __sinf(phi);
    float e2x = e1x * e1x - e1y * e1y;
    float e2y = 2.0f * e1x * e1y;
    float2 u00 = make_float2(0.5f * (1.0f + e1x),  0.5f * e1y);
    float2 u01 = make_float2(0.5f * (1.0f - e1x), -0.5f * e1y);
    float2 u10 = make_float2(0.5f * (e1x - e2x), 0.5f * (e1y - e2y));
    float2 u11 = make_float2(0.5f * (e1x + e2x), 0.5f * (e1y + e2y));
    if constexpr (Q >= 2) {
        bool bset = (lane >> (Q - 2)) & 1;
        float csx = bset ? u11.x : u00.x, csy = bset ? u11.y : u00.y;
        float cox = bset ? u10.x : u01.x, coy = bset ? u10.y : u01.y;
        #pragma unroll
        for (int r = 0; r < 4; ++r) {
            float ox = exq<Q>(a[r].x), oy = exq<Q>(a[r].y);
            float nx = csx * a[r].x - csy * a[r].y + cox * ox - coy * oy;
            float ny = csx * a[r].y + csy * a[r].x + cox * oy + coy * ox;
            a[r] = make_float2(nx, ny);
        }
    } else {
        float2 l, h;
        #define APPL(LO, HI)                                                        \
            l = a[LO]; h = a[HI];                                                   \
            a[LO] = make_float2(u00.x*l.x - u00.y*l.y + u01.x*h.x - u01.y*h.y,      \
                                u00.x*l.y + u00.y*l.x + u01.x*h.y + u01.y*h.x);     \
            a[HI] = make_float2(u10.x*l.x - u10.y*l.y + u11.x*h.x - u11.y*h.y,      \
                                u10.x*l.y + u10.y*l.x + u11.x*h.y + u11.y*h.x);
        if constexpr (Q == 0) { APPL(0, 2) APPL(1, 3) }
        else                  { APPL(0, 1) APPL(2, 3) }
        #undef APPL
    }
}

template<int Q1, int Q2>
__device__ __forceinline__ void convg(float2 a[4], const float* __restrict__ p, int lane) {
    rzg<Q2>(a, -0.5f * PI_F, lane);
    cxg<Q2, Q1>(a, lane);
    rzg<Q1>(a, p[0], lane);
    ryg<Q2>(a, p[1], lane);
    cxg<Q1, Q2>(a, lane);
    ryg<Q2>(a, p[2], lane);
    cxg<Q2, Q1>(a, lane);
    rzg<Q1>(a, 0.5f * PI_F, lane);
}

template<int Q1, int Q2>
__device__ __forceinline__ void poolg(float2 a[4], const float* __restrict__ p, int lane) {
    rzg<Q2>(a, -0.5f * PI_F, lane);
    cxg<Q2, Q1>(a, lane);
    rzg<Q1>(a, p[0], lane);
    ryg<Q2>(a, p[1], lane);
    cxg<Q1, Q2>(a, lane);
    ryg<Q2>(a, p[2], lane);
}

__global__ __launch_bounds__(256) void qcnn_kernel(const float* __restrict__ x,
                                                   const float* __restrict__ w,
                                                   float* __restrict__ out) {
    int lane = threadIdx.x & 63;
    int n = blockIdx.x * 4 + (threadIdx.x >> 6);   // sample = wave
    float2 a[4];
    a[0] = make_float2(lane == 0 ? 1.0f : 0.0f, 0.0f);
    a[1] = make_float2(0.0f, 0.0f);
    a[2] = make_float2(0.0f, 0.0f);
    a[3] = make_float2(0.0f, 0.0f);

    const float* xr = x + n * 8;
    featg<0>(a, xr[0], lane);
    featg<1>(a, xr[1], lane);
    featg<2>(a, xr[2], lane);
    featg<3>(a, xr[3], lane);
    featg<4>(a, xr[4], lane);
    featg<5>(a, xr[5], lane);
    featg<6>(a, xr[6], lane);
    featg<7>(a, xr[7], lane);

    convg<0,1>(a, w + 0,  lane);
    convg<2,3>(a, w + 3,  lane);
    convg<4,5>(a, w + 6,  lane);
    convg<6,7>(a, w + 9,  lane);
    poolg<0,1>(a, w + 12, lane);
    poolg<2,3>(a, w + 15, lane);
    poolg<4,5>(a, w + 18, lane);
    poolg<6,7>(a, w + 21, lane);
    convg<0,1>(a, w + 24, lane);
    convg<2,3>(a, w + 27, lane);
    poolg<0,1>(a, w + 30, lane);
    poolg<2,3>(a, w + 33, lane);
    convg<0,1>(a, w + 36, lane);
    poolg<0,1>(a, w + 39, lane);

    // <Z_q7>: q7 = lane bit5
    float ssum = 0.f;
    #pragma unroll
    for (int r = 0; r < 4; ++r)
        ssum += a[r].x * a[r].x + a[r].y * a[r].y;
    ssum = (lane & 32) ? -ssum : ssum;
    #pragma unroll
    for (int m = 1; m < 64; m <<= 1)
        ssum += __shfl_xor(ssum, m, 64);
    if (lane == 0) out[n] = ssum;
}

// ---------------------------------------------------------------------------
// QLSTM closed-form qgate: c_i = cos(v_i + th_i):
//   rows = [c1c2c3, c0c1, c0c1c2, c0c1c2c3]
// lane = b*4 + q. Dual role: computes GATE q's 4 rows; owns STATE row q.
// Nonlinearity unified: n = A + B*rcp(exp(k*r)+1)
//   sigma: A=0,B=1,k=-1   tanh: A=1,B=-2,k=2
// Routing: 16 DPP quad broadcasts + 12 cndmask row-picks; h re-broadcast 4 DPP.
// ---------------------------------------------------------------------------

template<int CTRL>
__device__ __forceinline__ float bq(float v) {   // quad_perm broadcast
    return __int_as_float(__builtin_amdgcn_update_dpp(0, __float_as_int(v), CTRL, 0xF, 0xF, true));
}

__device__ __forceinline__ float pick4(bool b0, bool b1, float a0, float a1, float a2, float a3) {
    float t01 = b0 ? a1 : a0;
    float t23 = b0 ? a3 : a2;
    return b1 ? t23 : t01;
}

__global__ __launch_bounds__(64) void qlstm_kernel(
    const float* __restrict__ qc,
    const float* __restrict__ thf, const float* __restrict__ thi,
    const float* __restrict__ thg, const float* __restrict__ tho,
    const float* __restrict__ Wf, const float* __restrict__ bf,
    const float* __restrict__ Wi, const float* __restrict__ bi,
    const float* __restrict__ Wg, const float* __restrict__ bg,
    const float* __restrict__ Wo, const float* __restrict__ bo,
    const float* __restrict__ Wh, const float* __restrict__ bh,
    float* __restrict__ out) {
    __shared__ __align__(16) float qsh[16 * 132];   // padded rows: conflict-free
    int lane = threadIdx.x;

    const float4* qc4 = (const float4*)qc;
    #pragma unroll
    for (int k = 0; k < 8; ++k) {
        int i = k * 64 + lane;
        float4 v = qc4[i];
        int b = i >> 5;
        int t = (i & 31) << 2;
        *(float4*)&qsh[b * 132 + t] = v;
    }
    __builtin_amdgcn_wave_barrier();     // single wave: LDS ops program-ordered

    int b = lane >> 2, q = lane & 3;
    bool qb0 = q & 1, qb1 = q & 2;
    const float* Wp = (q == 0) ? Wf : (q == 1) ? Wi : (q == 2) ? Wg : Wo;
    const float* bp = (q == 0) ? bf : (q == 1) ? bi : (q == 2) ? bg : bo;
    const float* tp = (q == 0) ? thf : (q == 1) ? thi : (q == 2) ? thg : tho;

    float W[20], av[4];
    #pragma unroll
    for (int k = 0; k < 20; ++k) W[k] = Wp[k];
    #pragma unroll
    for (int r = 0; r < 4; ++r) av[r] = bp[r] + tp[r];

    // gate-q nonlinearity constants (tanh for q==2, sigmoid otherwise)
    float nA = (q == 2) ? 1.0f : 0.0f;
    float nB = (q == 2) ? -2.0f : 1.0f;
    float nK = (q == 2) ? 2.0f : -1.0f;

    float c = 0.f;                       // state row q only
    float h0 = 0.f, h1 = 0.f, h2 = 0.f, h3 = 0.f;   // broadcast h (all rows)
    const float* qrow = &qsh[b * 132];
    float xv = qrow[0];

    for (int t = 0; t < 128; ++t) {
        float xn = qrow[t + 1];          // prefetch (t=127 reads row padding, unused)
        float vA = av[0] + W[0]*xv  + W[1]*h0  + W[2]*h1  + W[3]*h2  + W[4]*h3;
        float vB = av[1] + W[5]*xv  + W[6]*h0  + W[7]*h1  + W[8]*h2  + W[9]*h3;
        float vC = av[2] + W[10]*xv + W[11]*h0 + W[12]*h1 + W[13]*h2 + W[14]*h3;
        float vD = av[3] + W[15]*xv + W[16]*h0 + W[17]*h1 + W[18]*h2 + W[19]*h3;
        float cA = __cosf(vA), cB = __cosf(vB), cC = __cosf(vC), cD = __cosf(vD);
        float r1 = cA * cB, r2 = r1 * cC, r3 = r2 * cD, r0 = cB * (cC * cD);
        // unified nonlinearity for this lane's gate
        float E0 = __expf(nK * r0), E1 = __expf(nK * r1);
        float E2 = __expf(nK * r2), E3 = __expf(nK * r3);
        float n0 = nA + nB * rcpf(E0 + 1.0f);
        float n1 = nA + nB * rcpf(E1 + 1.0f);
        float n2 = nA + nB * rcpf(E2 + 1.0f);
        float n3 = nA + nB * rcpf(E3 + 1.0f);
        // broadcast all 16 gate x row values across the quad
        float F0 = bq<0x00>(n0), F1 = bq<0x00>(n1), F2 = bq<0x00>(n2), F3 = bq<0x00>(n3);
        float I0 = bq<0x55>(n0), I1 = bq<0x55>(n1), I2 = bq<0x55>(n2), I3 = bq<0x55>(n3);
        float G0 = bq<0xAA>(n0), G1 = bq<0xAA>(n1), G2 = bq<0xAA>(n2), G3 = bq<0xAA>(n3);
        float O0 = bq<0xFF>(n0), O1 = bq<0xFF>(n1), O2 = bq<0xFF>(n2), O3 = bq<0xFF>(n3);
        // pick own row q
        float F = pick4(qb0, qb1, F0, F1, F2, F3);
        float I = pick4(qb0, qb1, I0, I1, I2, I3);
        float G = pick4(qb0, qb1, G0, G1, G2, G3);
        float O = pick4(qb0, qb1, O0, O1, O2, O3);
        c = F * c + I * G;
        float Ec = __expf(2.0f * c);
        float tau = 1.0f - 2.0f * rcpf(Ec + 1.0f);
        float hq = O * tau;
        h0 = bq<0x00>(hq);
        h1 = bq<0x55>(hq);
        h2 = bq<0xAA>(hq);
        h3 = bq<0xFF>(hq);
        xv = xn;
    }

    if (q == 0)
        out[2048 + b] = bh[0] + Wh[0]*h0 + Wh[1]*h1 + Wh[2]*h2 + Wh[3]*h3;
}

extern "C" void kernel_launch(void* const* d_in, const int* in_sizes, int n_in,
                              void* d_out, int out_size, void* d_ws, size_t ws_size,
                              hipStream_t stream) {
    const float* x = (const float*)d_in[0];
    const float* w = (const float*)d_in[1];
    float* out = (float*)d_out;

    qcnn_kernel<<<512, 256, 0, stream>>>(x, w, out);
    qlstm_kernel<<<1, 64, 0, stream>>>(
        out,
        (const float*)d_in[2], (const float*)d_in[3],
        (const float*)d_in[4], (const float*)d_in[5],
        (const float*)d_in[6], (const float*)d_in[7],
        (const float*)d_in[8], (const float*)d_in[9],
        (const float*)d_in[10], (const float*)d_in[11],
        (const float*)d_in[12], (const float*)d_in[13],
        (const float*)d_in[14], (const float*)d_in[15],
        out);
}